// Round 8
// baseline (258.416 us; speedup 1.0000x reference)
//
#include <hip/hip_runtime.h>

// Problem constants
#define T_DIM   100
#define N_NODES 25
#define C_DIM   128
#define G_TOTAL 6400          // B*T
#define GNV     3200          // N_NODES * C_DIM (per-graph elements)
#define TOT_ELEM 20480000     // G_TOTAL * GNV
#define CNT_PER_T 204800.0f   // B * N * C

// ws float offsets
#define WS_A2P  0             // 1024 bf16 (512 floats): A2 bf16, zero-padded 32x32 [m][k]
#define WS_RS1  640           // 25 floats: rowsum(Ahat)
#define WS_BW   768           // 128 floats: W2^T b1
#define WS_SUM  1024          // 100 floats: per-t sum   (zeroed each call)
#define WS_SSQ  1152          // 100 floats: per-t sumsq
#define WS_W12T 2048          // 16384 bf16 (= 8192 floats): W12^T, [c][v]
#define WS_HB   16384         // bf16 H buffer (TOT_ELEM ushorts = 40.96 MB), if ws fits

// Y_T layout in LDS: [g][c][row], row-stride 36 shorts (72 B: 18-dword stride,
// gcd(18,32)=2 -> 16-bank spread, 2-way free; 8B-aligned for b64 access).
#define YSTR  36
#define YGSTR (128 * YSTR)    // 4608 shorts per graph

typedef __attribute__((ext_vector_type(8))) short short8;
typedef __attribute__((ext_vector_type(4))) float f32x4;

__device__ __forceinline__ unsigned short f2bf(float f) {
  unsigned int u = __float_as_uint(f);
  u += 0x7FFFu + ((u >> 16) & 1u);   // RNE
  return (unsigned short)(u >> 16);
}
__device__ __forceinline__ float bf2f(unsigned short h) {
  return __uint_as_float(((unsigned int)h) << 16);
}
__device__ __forceinline__ unsigned int pack2bf(float a, float b) {
  return (unsigned int)f2bf(a) | ((unsigned int)f2bf(b) << 16);
}

// ---------------------------------------------------------------------------
// k_pre: blocks 0..63 = W12T/bw prep; block 64 = adjacency prep (independent).
__global__ void k_pre(const int* __restrict__ edge, const float* __restrict__ W1,
                      const float* __restrict__ W2, const float* __restrict__ b1,
                      float* __restrict__ wsf) {
  __shared__ float sA[N_NODES * N_NODES];
  __shared__ float sA2[N_NODES * N_NODES];
  __shared__ float sdeg[N_NODES];
  __shared__ float sdis[N_NODES];
  const int tid = threadIdx.x;  // 256

  if (blockIdx.x < 64) {
    // W12T[c][v] = sum_u W1[v][u]*W2[u][c]  (bf16), bw = W2^T b1.
    int j = blockIdx.x * 256 + tid;          // 16384
    int c = j & 127, v = j >> 7;             // v wave-uniform
    float acc = 0.f;
#pragma unroll 8
    for (int u = 0; u < 128; u++) acc = fmaf(W1[v * 128 + u], W2[u * 128 + c], acc);
    ((unsigned short*)(wsf + WS_W12T))[c * 128 + v] = f2bf(acc);
    if (j < 128) {
      float a2 = 0.f;
      for (int u = 0; u < 128; u++) a2 = fmaf(W2[u * 128 + j], b1[u], a2);
      wsf[WS_BW + j] = a2;
    }
    return;
  }

  // ---- block 64: normalized adjacency, A2 = Ahat^2 (bf16 padded), rowsums.
  if (tid < N_NODES) sdeg[tid] = 0.f;
  for (int j = tid; j < N_NODES * N_NODES; j += 256) sA[j] = 0.f;
  __syncthreads();
  if (tid < 64) atomicAdd(&sdeg[edge[64 + tid]], 1.f);  // tgt occurrences
  __syncthreads();
  if (tid < N_NODES) sdis[tid] = rsqrtf(sdeg[tid] + 1.f);  // +1 self-loop
  __syncthreads();
  if (tid < 64) {
    int s = edge[tid], tg = edge[64 + tid];
    atomicAdd(&sA[tg * N_NODES + s], sdis[s] * sdis[tg]);
  }
  __syncthreads();
  if (tid < N_NODES) atomicAdd(&sA[tid * N_NODES + tid], sdis[tid] * sdis[tid]);
  __syncthreads();
  for (int j = tid; j < N_NODES * N_NODES; j += 256) {
    int n = j / N_NODES, m = j - n * N_NODES;
    float acc = 0.f;
    for (int k = 0; k < N_NODES; k++) acc = fmaf(sA[n * N_NODES + k], sA[k * N_NODES + m], acc);
    sA2[j] = acc;
  }
  __syncthreads();
  // A2 bf16, zero-padded to 32x32 row-major [m][k]
  for (int j = tid; j < 1024; j += 256) {
    int m = j >> 5, k = j & 31;
    float v = (m < N_NODES && k < N_NODES) ? sA2[m * N_NODES + k] : 0.f;
    ((unsigned short*)(wsf + WS_A2P))[j] = f2bf(v);
  }
  if (tid < N_NODES) {
    float rs = 0.f;
    for (int m = 0; m < N_NODES; m++) rs += sA[tid * N_NODES + m];
    wsf[WS_RS1 + tid] = rs;
  }
  if (tid < T_DIM) { wsf[WS_SUM + tid] = 0.f; wsf[WS_SSQ + tid] = 0.f; }
}

// ---------------------------------------------------------------------------
// shared building blocks for the MFMA pipeline
__device__ __forceinline__ void load_bfr(const unsigned short* __restrict__ Wg,
                                         int wv, int quad, int l16, short8 bfr[2][4]) {
#pragma unroll
  for (int nt = 0; nt < 2; nt++) {
    const short8* rp = (const short8*)&Wg[(wv * 32 + nt * 16 + l16) * 128];
#pragma unroll
    for (int ks = 0; ks < 4; ks++) bfr[nt][ks] = rp[(ks << 2) | quad];
  }
}

__device__ __forceinline__ void load_a2f(const unsigned short* __restrict__ A2p,
                                         int quad, int l16, short8 a2f[2]) {
#pragma unroll
  for (int mt2 = 0; mt2 < 2; mt2++)
    a2f[mt2] = *(const short8*)&A2p[(mt2 * 16 + l16) * 32 + quad * 8];
}

// Stage X: zero pad rows + load 1600 chunks (8 fp32 -> 8 bf16, swizzled 16B).
__device__ __forceinline__ void stage_x_global(unsigned short* __restrict__ LB,
                                               const float* __restrict__ xb, int tid) {
  for (int j = tid; j < 12 * 128; j += 256) {
    int pr = j >> 7;                       // 0..11
    int g = pr / 3, rr = pr - (pr / 3) * 3;
    LB[(g * 28 + 25 + rr) * 128 + (j & 127)] = 0;
  }
  for (int idx = tid; idx < 1600; idx += 256) {
    int row = idx >> 4;                    // 0..99  (4 graphs x 25 rows)
    int c8  = (idx & 15) << 3;             // v0 = 0..120 step 8
    int g = (row * 41) >> 10;              // row / 25 (exact for row<100)
    int n = row - g * 25;
    const f32x4* xp = (const f32x4*)(xb + g * (T_DIM * GNV) + n * 128 + c8);
    f32x4 f0 = __builtin_nontemporal_load(xp);
    f32x4 f1 = __builtin_nontemporal_load(xp + 1);
    uint4 w;
    w.x = pack2bf(f0[0], f0[1]); w.y = pack2bf(f0[2], f0[3]);
    w.z = pack2bf(f1[0], f1[1]); w.w = pack2bf(f1[2], f1[3]);
    int r = g * 28 + n;
    *(uint4*)&LB[r * 128 + (c8 ^ ((r & 15) << 3))] = w;
  }
}

// Stage 1: Y = X * W12. Wave covers c in [wv*32,+32). 56 MFMA.
__device__ __forceinline__ void do_stage1(const unsigned short* __restrict__ LB,
                                          const short8 bfr[2][4], int quad, int l16,
                                          f32x4 acc[7][2]) {
#pragma unroll
  for (int mt = 0; mt < 7; mt++)
#pragma unroll
    for (int nt = 0; nt < 2; nt++)
#pragma unroll
      for (int r = 0; r < 4; r++) acc[mt][nt][r] = 0.f;
#pragma unroll
  for (int ks = 0; ks < 4; ks++) {
    const int cc = (ks << 2) | quad;
#pragma unroll
    for (int mt = 0; mt < 7; mt++) {
      int arow = mt * 16 + l16;
      short8 afr = *(const short8*)&LB[arow * 128 + ((cc ^ (arow & 15)) << 3)];
#pragma unroll
      for (int nt = 0; nt < 2; nt++)
        acc[mt][nt] = __builtin_amdgcn_mfma_f32_16x16x32_bf16(afr, bfr[nt][ks], acc[mt][nt], 0, 0, 0);
    }
  }
}

// Write Y -> Y_T (bf16) + zero pad rows 28..31.
__device__ __forceinline__ void write_yt(unsigned short* __restrict__ LB,
                                         const f32x4 acc[7][2], int wv, int quad,
                                         int l16, int tid) {
#pragma unroll
  for (int mt = 0; mt < 7; mt++) {
    int row0 = mt * 16 + quad * 4;
    int g = row0 / 28;
    int rl = row0 - g * 28;                // multiple of 4 -> 8B aligned
#pragma unroll
    for (int nt = 0; nt < 2; nt++) {
      int c = wv * 32 + nt * 16 + l16;
      uint2 p;
      p.x = pack2bf(acc[mt][nt][0], acc[mt][nt][1]);
      p.y = pack2bf(acc[mt][nt][2], acc[mt][nt][3]);
      *(uint2*)&LB[g * YGSTR + c * YSTR + rl] = p;
    }
  }
  uint2 z; z.x = 0u; z.y = 0u;
  for (int j = tid; j < 512; j += 256) {
    int g = j >> 7, c = j & 127;
    *(uint2*)&LB[g * YGSTR + c * YSTR + 28] = z;
  }
}

// Stage 2: H_g = A2 * Y_g (wave = graph) + epilogue: bias, bf16 store, stats.
__device__ __forceinline__ void do_stage2_epi(const unsigned short* __restrict__ LB,
    const short8 a2f[2], const float* __restrict__ sBW, const float* __restrict__ sB2,
    const float* __restrict__ rs1, unsigned short* __restrict__ hb, int obase,
    int wv, int quad, int l16, float& sum, float& ssq) {
#pragma unroll
  for (int half = 0; half < 2; half++) {
    f32x4 acc2[2][4];
#pragma unroll
    for (int mt2 = 0; mt2 < 2; mt2++)
#pragma unroll
      for (int nt = 0; nt < 4; nt++)
#pragma unroll
        for (int r = 0; r < 4; r++) acc2[mt2][nt][r] = 0.f;

#pragma unroll
    for (int nt = 0; nt < 4; nt++) {
      int c = (half * 4 + nt) * 16 + l16;
      int base = wv * YGSTR + c * YSTR + quad * 8;
      uint2 lo = *(const uint2*)&LB[base];
      uint2 hi = *(const uint2*)&LB[base + 4];
      uint4 w; w.x = lo.x; w.y = lo.y; w.z = hi.x; w.w = hi.y;
      short8 bf = __builtin_bit_cast(short8, w);
#pragma unroll
      for (int mt2 = 0; mt2 < 2; mt2++)
        acc2[mt2][nt] = __builtin_amdgcn_mfma_f32_16x16x32_bf16(a2f[mt2], bf, acc2[mt2][nt], 0, 0, 0);
    }
#pragma unroll
    for (int mt2 = 0; mt2 < 2; mt2++) {
#pragma unroll
      for (int nt = 0; nt < 4; nt++) {
        int c = (half * 4 + nt) * 16 + l16;
        float bw = sBW[c], bb = sB2[c];
#pragma unroll
        for (int r = 0; r < 4; r++) {
          int m = mt2 * 16 + quad * 4 + r;
          if (m < N_NODES) {
            float v = acc2[mt2][nt][r] + rs1[m] * bw + bb;
            unsigned short hv = f2bf(v);
            float vq = bf2f(hv);           // stats on rounded H (self-consistent)
            hb[obase + m * 128 + c] = hv;
            sum += vq;
            ssq += vq * vq;
          }
        }
      }
    }
  }
}

// ---------------------------------------------------------------------------
// k_main_h2: 800 blocks x 2 chunks (same t; bq and bq+8). Chunk B's global
// x-loads are issued at the top of stage-2-A so their latency hides under
// MFMA + epilogue stores; B stages to LDS from registers afterwards.
__global__ __launch_bounds__(256, 4) void k_main_h2(const float* __restrict__ x,
                                                    const float* __restrict__ b2,
                                                    const float* __restrict__ wsc,
                                                    float* __restrict__ stats,
                                                    unsigned short* __restrict__ hb) {
  __shared__ __align__(16) unsigned short LB[4 * YGSTR];  // 36864 B union
  __shared__ float sBW[128];
  __shared__ float sB2[128];
  __shared__ float rs1[32];
  __shared__ float red[8];
  const int tid = threadIdx.x;
  const int bid = blockIdx.x;
  const int t = bid % T_DIM;
  const int bqA = bid / T_DIM;           // 0..7
  const int bqB = bqA + 8;               // 8..15 (chunk bid+800: same t)
  const int wv = tid >> 6, lane = tid & 63, quad = lane >> 4, l16 = lane & 15;
  const unsigned short* Wg = (const unsigned short*)(wsc + WS_W12T);
  const unsigned short* A2p = (const unsigned short*)(wsc + WS_A2P);

  if (tid < 128) {
    sBW[tid] = wsc[WS_BW + tid];
    if (tid < N_NODES) rs1[tid] = wsc[WS_RS1 + tid];
  } else {
    sB2[tid - 128] = b2[tid - 128];
  }

  // ---- chunk A: stage X to LDS
  stage_x_global(LB, x + (bqA * 4 * T_DIM + t) * GNV, tid);
  short8 bfr[2][4];
  load_bfr(Wg, wv, quad, l16, bfr);
  __syncthreads();

  f32x4 acc[7][2];
  do_stage1(LB, bfr, quad, l16, acc);
  __syncthreads();                       // X_A reads done; LB -> Y_T_A

  write_yt(LB, acc, wv, quad, l16, tid);
  __syncthreads();                       // Y_T_A visible

  // ---- prefetch chunk B x into regs (overlaps stage-2-A compute/stores)
  uint4 stB[7];
  const int cnB = (tid < 64) ? 7 : 6;    // wave-uniform (wave0: 7, others: 6)
  {
    const float* xbB = x + (bqB * 4 * T_DIM + t) * GNV;
#pragma unroll
    for (int i = 0; i < 7; i++) {
      if (i < cnB) {
        int idx = tid + (i << 8);
        int row = idx >> 4, c8 = (idx & 15) << 3;
        int g = (row * 41) >> 10, n = row - g * 25;
        const f32x4* xp = (const f32x4*)(xbB + g * (T_DIM * GNV) + n * 128 + c8);
        f32x4 f0 = __builtin_nontemporal_load(xp);
        f32x4 f1 = __builtin_nontemporal_load(xp + 1);
        uint4 w;
        w.x = pack2bf(f0[0], f0[1]); w.y = pack2bf(f0[2], f0[3]);
        w.z = pack2bf(f1[0], f1[1]); w.w = pack2bf(f1[2], f1[3]);
        stB[i] = w;
      }
    }
  }

  // ---- stage 2 A + epilogue
  short8 a2f[2];
  load_a2f(A2p, quad, l16, a2f);
  float sum = 0.f, ssq = 0.f;
  do_stage2_epi(LB, a2f, sBW, sB2, rs1, hb,
                ((bqA * 4 + wv) * T_DIM + t) * GNV, wv, quad, l16, sum, ssq);
  __syncthreads();                       // Y_T_A reads done; LB -> X_B view

  // ---- chunk B: stage X from regs
  for (int j = tid; j < 12 * 128; j += 256) {
    int pr = j >> 7;
    int g = pr / 3, rr = pr - (pr / 3) * 3;
    LB[(g * 28 + 25 + rr) * 128 + (j & 127)] = 0;
  }
#pragma unroll
  for (int i = 0; i < 7; i++) {
    if (i < cnB) {
      int idx = tid + (i << 8);
      int row = idx >> 4, c8 = (idx & 15) << 3;
      int g = (row * 41) >> 10, n = row - g * 25;
      int r = g * 28 + n;
      *(uint4*)&LB[r * 128 + (c8 ^ ((r & 15) << 3))] = stB[i];
    }
  }
  load_bfr(Wg, wv, quad, l16, bfr);      // reload (kept live range short)
  __syncthreads();

  do_stage1(LB, bfr, quad, l16, acc);
  __syncthreads();

  write_yt(LB, acc, wv, quad, l16, tid);
  __syncthreads();

  load_a2f(A2p, quad, l16, a2f);
  do_stage2_epi(LB, a2f, sBW, sB2, rs1, hb,
                ((bqB * 4 + wv) * T_DIM + t) * GNV, wv, quad, l16, sum, ssq);

  // ---- combined stats reduce: one atomic pair per block
#pragma unroll
  for (int off = 32; off > 0; off >>= 1) {
    sum += __shfl_down(sum, off, 64);
    ssq += __shfl_down(ssq, off, 64);
  }
  if (lane == 0) { red[wv] = sum; red[4 + wv] = ssq; }
  __syncthreads();
  if (tid == 0) {
    atomicAdd(&stats[t], red[0] + red[1] + red[2] + red[3]);
    atomicAdd(&stats[128 + t], red[4] + red[5] + red[6] + red[7]);
  }
}

// ---------------------------------------------------------------------------
// k_norm_h: read bf16 H (L3-hot), write fp32 out ONCE (non-temporal).
__global__ __launch_bounds__(256) void k_norm_h(const unsigned short* __restrict__ hb,
                                                const float* __restrict__ stats,
                                                const float* __restrict__ gamma,
                                                const float* __restrict__ beta,
                                                float* __restrict__ out) {
  const int i16 = (blockIdx.x * 256 + threadIdx.x) * 16;
  const int t = (i16 / GNV) % T_DIM;         // 16 consecutive share t (GNV%16==0)
  const float inv = 1.f / CNT_PER_T;
  float s = stats[t], q = stats[128 + t];
  float mean = s * inv;
  float var = fmaf(q, inv, -mean * mean);
  float rstd = rsqrtf(var + 1e-5f);
  float gm = gamma[t] * rstd;
  float bt = fmaf(-mean, gm, beta[t]);
  uint4 h0 = *(const uint4*)(hb + i16);
  uint4 h1 = *(const uint4*)(hb + i16 + 8);
  unsigned int hw[8] = {h0.x, h0.y, h0.z, h0.w, h1.x, h1.y, h1.z, h1.w};
#pragma unroll
  for (int k = 0; k < 4; k++) {
    unsigned int a = hw[2 * k], b = hw[2 * k + 1];
    f32x4 o;
    o[0] = fmaxf(fmaf(bf2f((unsigned short)(a & 0xFFFF)), gm, bt), 0.f);
    o[1] = fmaxf(fmaf(bf2f((unsigned short)(a >> 16)),    gm, bt), 0.f);
    o[2] = fmaxf(fmaf(bf2f((unsigned short)(b & 0xFFFF)), gm, bt), 0.f);
    o[3] = fmaxf(fmaf(bf2f((unsigned short)(b >> 16)),    gm, bt), 0.f);
    __builtin_nontemporal_store(o, (f32x4*)(out + i16 + 4 * k));
  }
}

// ---------------------------------------------------------------------------
// Fallback path (proven round-1/round-5 fp32 variants), used only if ws small.
__global__ __launch_bounds__(256, 4) void k_main_f(const float* __restrict__ x,
                                                   const float* __restrict__ b2,
                                                   const float* __restrict__ wsc,
                                                   float* __restrict__ stats,
                                                   float* __restrict__ outf) {
  __shared__ __align__(16) unsigned short LB[4 * YGSTR];
  __shared__ float sBW[128];
  __shared__ float sB2[128];
  __shared__ float rs1[32];
  __shared__ float red[8];
  const int tid = threadIdx.x;
  const int bid = blockIdx.x;
  const int t = bid % T_DIM;
  const int bq = bid / T_DIM;
  const int wv = tid >> 6, lane = tid & 63, quad = lane >> 4, l16 = lane & 15;
  const unsigned short* Wg = (const unsigned short*)(wsc + WS_W12T);
  const unsigned short* A2p = (const unsigned short*)(wsc + WS_A2P);

  if (tid < 128) {
    sBW[tid] = wsc[WS_BW + tid];
    if (tid < N_NODES) rs1[tid] = wsc[WS_RS1 + tid];
  } else {
    sB2[tid - 128] = b2[tid - 128];
  }
  stage_x_global(LB, x + (bq * 4 * T_DIM + t) * GNV, tid);
  short8 bfr[2][4];
  load_bfr(Wg, wv, quad, l16, bfr);
  __syncthreads();
  f32x4 acc[7][2];
  do_stage1(LB, bfr, quad, l16, acc);
  __syncthreads();
  write_yt(LB, acc, wv, quad, l16, tid);
  __syncthreads();
  short8 a2f[2];
  load_a2f(A2p, quad, l16, a2f);
  const int obase = ((bq * 4 + wv) * T_DIM + t) * GNV;
  float sum = 0.f, ssq = 0.f;
#pragma unroll
  for (int half = 0; half < 2; half++) {
    f32x4 acc2[2][4];
#pragma unroll
    for (int mt2 = 0; mt2 < 2; mt2++)
#pragma unroll
      for (int nt = 0; nt < 4; nt++)
#pragma unroll
        for (int r = 0; r < 4; r++) acc2[mt2][nt][r] = 0.f;
#pragma unroll
    for (int nt = 0; nt < 4; nt++) {
      int c = (half * 4 + nt) * 16 + l16;
      int base = wv * YGSTR + c * YSTR + quad * 8;
      uint2 lo = *(const uint2*)&LB[base];
      uint2 hi = *(const uint2*)&LB[base + 4];
      uint4 w; w.x = lo.x; w.y = lo.y; w.z = hi.x; w.w = hi.y;
      short8 bf = __builtin_bit_cast(short8, w);
#pragma unroll
      for (int mt2 = 0; mt2 < 2; mt2++)
        acc2[mt2][nt] = __builtin_amdgcn_mfma_f32_16x16x32_bf16(a2f[mt2], bf, acc2[mt2][nt], 0, 0, 0);
    }
#pragma unroll
    for (int mt2 = 0; mt2 < 2; mt2++) {
#pragma unroll
      for (int nt = 0; nt < 4; nt++) {
        int c = (half * 4 + nt) * 16 + l16;
        float bw = sBW[c], bb = sB2[c];
#pragma unroll
        for (int r = 0; r < 4; r++) {
          int m = mt2 * 16 + quad * 4 + r;
          if (m < N_NODES) {
            float v = acc2[mt2][nt][r] + rs1[m] * bw + bb;
            outf[obase + m * 128 + c] = v;
            sum += v;
            ssq += v * v;
          }
        }
      }
    }
  }
#pragma unroll
  for (int off = 32; off > 0; off >>= 1) {
    sum += __shfl_down(sum, off, 64);
    ssq += __shfl_down(ssq, off, 64);
  }
  if (lane == 0) { red[wv] = sum; red[4 + wv] = ssq; }
  __syncthreads();
  if (tid == 0) {
    atomicAdd(&stats[t], red[0] + red[1] + red[2] + red[3]);
    atomicAdd(&stats[128 + t], red[4] + red[5] + red[6] + red[7]);
  }
}

#define NORM_STR  1280000   // float4 stride between a thread's 4 accesses
__global__ __launch_bounds__(256) void k_norm_f(float* __restrict__ out,
                                                const float* __restrict__ stats,
                                                const float* __restrict__ gamma,
                                                const float* __restrict__ beta) {
  const int i0 = blockIdx.x * 256 + threadIdx.x;
  const float inv = 1.f / CNT_PER_T;
  float4 h[4];
  float g[4], bb[4];
  int base[4];
#pragma unroll
  for (int k = 0; k < 4; k++) {
    int i4 = i0 + k * NORM_STR;
    base[k] = i4 * 4;
    int t = (base[k] / GNV) % T_DIM;
    float s = stats[t], q = stats[128 + t];
    float mean = s * inv;
    float var = fmaf(q, inv, -mean * mean);
    float rstd = rsqrtf(var + 1e-5f);
    g[k] = gamma[t] * rstd;
    bb[k] = fmaf(-mean, g[k], beta[t]);
    h[k] = *(const float4*)(out + base[k]);
  }
#pragma unroll
  for (int k = 0; k < 4; k++) {
    float4 v = h[k];
    v.x = fmaxf(fmaf(v.x, g[k], bb[k]), 0.f);
    v.y = fmaxf(fmaf(v.y, g[k], bb[k]), 0.f);
    v.z = fmaxf(fmaf(v.z, g[k], bb[k]), 0.f);
    v.w = fmaxf(fmaf(v.w, g[k], bb[k]), 0.f);
    *(float4*)(out + base[k]) = v;
  }
}

// ---------------------------------------------------------------------------
extern "C" void kernel_launch(void* const* d_in, const int* in_sizes, int n_in,
                              void* d_out, int out_size, void* d_ws, size_t ws_size,
                              hipStream_t stream) {
  const float* x     = (const float*)d_in[0];
  const int*   edge  = (const int*)d_in[1];
  const float* W1    = (const float*)d_in[2];
  const float* b1    = (const float*)d_in[3];
  const float* W2    = (const float*)d_in[4];
  const float* b2    = (const float*)d_in[5];
  const float* gamma = (const float*)d_in[6];
  const float* beta  = (const float*)d_in[7];
  float* out = (float*)d_out;
  float* wsf = (float*)d_ws;

  k_pre<<<65, 256, 0, stream>>>(edge, W1, W2, b1, wsf);

  const size_t need = (size_t)WS_HB * 4 + (size_t)TOT_ELEM * 2;
  if (ws_size >= need) {
    unsigned short* hb = (unsigned short*)(wsf + WS_HB);
    k_main_h2<<<G_TOTAL / 8, 256, 0, stream>>>(x, b2, wsf, wsf + WS_SUM, hb);
    k_norm_h<<<TOT_ELEM / (256 * 16), 256, 0, stream>>>(hb, wsf + WS_SUM, gamma, beta, out);
  } else {
    k_main_f<<<G_TOTAL / 4, 256, 0, stream>>>(x, b2, wsf, wsf + WS_SUM, out);
    k_norm_f<<<NORM_STR / 256, 256, 0, stream>>>(out, wsf + WS_SUM, gamma, beta);
  }
}

// Round 9
// 257.839 us; speedup vs baseline: 1.0022x; 1.0022x over previous
//
#include <hip/hip_runtime.h>

// Problem constants
#define T_DIM   100
#define N_NODES 25
#define C_DIM   128
#define G_TOTAL 6400          // B*T
#define GNV     3200          // N_NODES * C_DIM (per-graph elements)
#define TOT_ELEM 20480000     // G_TOTAL * GNV
#define CNT_PER_T 204800.0f   // B * N * C

// ws float offsets
#define WS_A2P  0             // 1024 bf16 (512 floats): A2 bf16, zero-padded 32x32 [m][k]
#define WS_RS1  640           // 25 floats: rowsum(Ahat)
#define WS_BW   768           // 128 floats: W2^T b1
#define WS_SUM  1024          // 100 floats: per-t sum   (zeroed each call)
#define WS_SSQ  1152          // 100 floats: per-t sumsq
#define WS_W12T 2048          // 16384 bf16 (= 8192 floats): W12^T, [c][v]
#define WS_HB   16384         // bf16 H buffer (TOT_ELEM ushorts = 40.96 MB), if ws fits

// Y_T layout in LDS: [g][c][row], row-stride 36 shorts (72 B: 18-dword stride,
// gcd(18,32)=2 -> 16-bank spread, 2-way free; 8B-aligned for b64 access).
#define YSTR  36
#define YGSTR (128 * YSTR)    // 4608 shorts per graph

typedef __attribute__((ext_vector_type(8))) short short8;
typedef __attribute__((ext_vector_type(4))) float f32x4;

__device__ __forceinline__ unsigned short f2bf(float f) {
  unsigned int u = __float_as_uint(f);
  u += 0x7FFFu + ((u >> 16) & 1u);   // RNE
  return (unsigned short)(u >> 16);
}
__device__ __forceinline__ float bf2f(unsigned short h) {
  return __uint_as_float(((unsigned int)h) << 16);
}
__device__ __forceinline__ unsigned int pack2bf(float a, float b) {
  return (unsigned int)f2bf(a) | ((unsigned int)f2bf(b) << 16);
}

// ---------------------------------------------------------------------------
// k_pre: blocks 0..63 = W12T/bw prep; block 64 = adjacency prep (independent).
__global__ void k_pre(const int* __restrict__ edge, const float* __restrict__ W1,
                      const float* __restrict__ W2, const float* __restrict__ b1,
                      float* __restrict__ wsf) {
  __shared__ float sA[N_NODES * N_NODES];
  __shared__ float sA2[N_NODES * N_NODES];
  __shared__ float sdeg[N_NODES];
  __shared__ float sdis[N_NODES];
  const int tid = threadIdx.x;  // 256

  if (blockIdx.x < 64) {
    // W12T[c][v] = sum_u W1[v][u]*W2[u][c]  (bf16), bw = W2^T b1.
    int j = blockIdx.x * 256 + tid;          // 16384
    int c = j & 127, v = j >> 7;             // v wave-uniform
    float acc = 0.f;
#pragma unroll 8
    for (int u = 0; u < 128; u++) acc = fmaf(W1[v * 128 + u], W2[u * 128 + c], acc);
    ((unsigned short*)(wsf + WS_W12T))[c * 128 + v] = f2bf(acc);
    if (j < 128) {
      float a2 = 0.f;
      for (int u = 0; u < 128; u++) a2 = fmaf(W2[u * 128 + j], b1[u], a2);
      wsf[WS_BW + j] = a2;
    }
    return;
  }

  // ---- block 64: normalized adjacency, A2 = Ahat^2 (bf16 padded), rowsums.
  if (tid < N_NODES) sdeg[tid] = 0.f;
  for (int j = tid; j < N_NODES * N_NODES; j += 256) sA[j] = 0.f;
  __syncthreads();
  if (tid < 64) atomicAdd(&sdeg[edge[64 + tid]], 1.f);  // tgt occurrences
  __syncthreads();
  if (tid < N_NODES) sdis[tid] = rsqrtf(sdeg[tid] + 1.f);  // +1 self-loop
  __syncthreads();
  if (tid < 64) {
    int s = edge[tid], tg = edge[64 + tid];
    atomicAdd(&sA[tg * N_NODES + s], sdis[s] * sdis[tg]);
  }
  __syncthreads();
  if (tid < N_NODES) atomicAdd(&sA[tid * N_NODES + tid], sdis[tid] * sdis[tid]);
  __syncthreads();
  for (int j = tid; j < N_NODES * N_NODES; j += 256) {
    int n = j / N_NODES, m = j - n * N_NODES;
    float acc = 0.f;
    for (int k = 0; k < N_NODES; k++) acc = fmaf(sA[n * N_NODES + k], sA[k * N_NODES + m], acc);
    sA2[j] = acc;
  }
  __syncthreads();
  // A2 bf16, zero-padded to 32x32 row-major [m][k]
  for (int j = tid; j < 1024; j += 256) {
    int m = j >> 5, k = j & 31;
    float v = (m < N_NODES && k < N_NODES) ? sA2[m * N_NODES + k] : 0.f;
    ((unsigned short*)(wsf + WS_A2P))[j] = f2bf(v);
  }
  if (tid < N_NODES) {
    float rs = 0.f;
    for (int m = 0; m < N_NODES; m++) rs += sA[tid * N_NODES + m];
    wsf[WS_RS1 + tid] = rs;
  }
  if (tid < T_DIM) { wsf[WS_SUM + tid] = 0.f; wsf[WS_SSQ + tid] = 0.f; }
}

// ---------------------------------------------------------------------------
// shared building blocks
__device__ __forceinline__ void load_bfr(const unsigned short* __restrict__ Wg,
                                         int wv, int quad, int l16, short8 bfr[2][4]) {
#pragma unroll
  for (int nt = 0; nt < 2; nt++) {
    const short8* rp = (const short8*)&Wg[(wv * 32 + nt * 16 + l16) * 128];
#pragma unroll
    for (int ks = 0; ks < 4; ks++) bfr[nt][ks] = rp[(ks << 2) | quad];
  }
}

__device__ __forceinline__ void load_a2f(const unsigned short* __restrict__ A2p,
                                         int quad, int l16, short8 a2f[2]) {
#pragma unroll
  for (int mt2 = 0; mt2 < 2; mt2++)
    a2f[mt2] = *(const short8*)&A2p[(mt2 * 16 + l16) * 32 + quad * 8];
}

// Write Y -> Y_T (bf16) + zero pad rows 28..31.
__device__ __forceinline__ void write_yt(unsigned short* __restrict__ LB,
                                         const f32x4 acc[7][2], int wv, int quad,
                                         int l16, int tid) {
#pragma unroll
  for (int mt = 0; mt < 7; mt++) {
    int row0 = mt * 16 + quad * 4;
    int g = row0 / 28;
    int rl = row0 - g * 28;                // multiple of 4 -> 8B aligned
#pragma unroll
    for (int nt = 0; nt < 2; nt++) {
      int c = wv * 32 + nt * 16 + l16;
      uint2 p;
      p.x = pack2bf(acc[mt][nt][0], acc[mt][nt][1]);
      p.y = pack2bf(acc[mt][nt][2], acc[mt][nt][3]);
      *(uint2*)&LB[g * YGSTR + c * YSTR + rl] = p;
    }
  }
  uint2 z; z.x = 0u; z.y = 0u;
  for (int j = tid; j < 512; j += 256) {
    int g = j >> 7, c = j & 127;
    *(uint2*)&LB[g * YGSTR + c * YSTR + 28] = z;
  }
}

// Stage 2: H_g = A2 * Y_g (wave = graph) + epilogue: bias, bf16 store, stats.
__device__ __forceinline__ void do_stage2_epi(const unsigned short* __restrict__ LB,
    const short8 a2f[2], const float* __restrict__ sBW, const float* __restrict__ sB2,
    const float* __restrict__ rs1, unsigned short* __restrict__ hb, int obase,
    int wv, int quad, int l16, float& sum, float& ssq) {
#pragma unroll
  for (int half = 0; half < 2; half++) {
    f32x4 acc2[2][4];
#pragma unroll
    for (int mt2 = 0; mt2 < 2; mt2++)
#pragma unroll
      for (int nt = 0; nt < 4; nt++)
#pragma unroll
        for (int r = 0; r < 4; r++) acc2[mt2][nt][r] = 0.f;

#pragma unroll
    for (int nt = 0; nt < 4; nt++) {
      int c = (half * 4 + nt) * 16 + l16;
      int base = wv * YGSTR + c * YSTR + quad * 8;
      uint2 lo = *(const uint2*)&LB[base];
      uint2 hi = *(const uint2*)&LB[base + 4];
      uint4 w; w.x = lo.x; w.y = lo.y; w.z = hi.x; w.w = hi.y;
      short8 bf = __builtin_bit_cast(short8, w);
#pragma unroll
      for (int mt2 = 0; mt2 < 2; mt2++)
        acc2[mt2][nt] = __builtin_amdgcn_mfma_f32_16x16x32_bf16(a2f[mt2], bf, acc2[mt2][nt], 0, 0, 0);
    }
#pragma unroll
    for (int mt2 = 0; mt2 < 2; mt2++) {
#pragma unroll
      for (int nt = 0; nt < 4; nt++) {
        int c = (half * 4 + nt) * 16 + l16;
        float bw = sBW[c], bb = sB2[c];
#pragma unroll
        for (int r = 0; r < 4; r++) {
          int m = mt2 * 16 + quad * 4 + r;
          if (m < N_NODES) {
            float v = acc2[mt2][nt][r] + rs1[m] * bw + bb;
            unsigned short hv = f2bf(v);
            float vq = bf2f(hv);           // stats on rounded H (self-consistent)
            hb[obase + m * 128 + c] = hv;
            sum += vq;
            ssq += vq * vq;
          }
        }
      }
    }
  }
}

// ---------------------------------------------------------------------------
// k_main_h3: stage-1 A-fragments loaded DIRECTLY from global x (no X-LDS
// staging, no stage-1 barriers). 56 independent 16B loads/lane interleave
// with MFMA across the whole stage -> memory pipe busy throughout. Waves
// redundantly read the same 57KB x-tile (4x) -> L2-absorbed. LDS holds only
// Y_T; single __syncthreads between Y_T write and stage-2 read.
__global__ __launch_bounds__(256, 4) void k_main_h3(const float* __restrict__ x,
                                                    const float* __restrict__ b2,
                                                    const float* __restrict__ wsc,
                                                    float* __restrict__ stats,
                                                    unsigned short* __restrict__ hb) {
  __shared__ __align__(16) unsigned short LB[4 * YGSTR];  // Y_T only (36864 B)
  __shared__ float sBW[128];
  __shared__ float sB2[128];
  __shared__ float rs1[32];
  __shared__ float red[8];
  const int tid = threadIdx.x;
  const int bid = blockIdx.x;
  const int t = bid % T_DIM;
  const int bq = bid / T_DIM;
  const int wv = tid >> 6, lane = tid & 63, quad = lane >> 4, l16 = lane & 15;
  const unsigned short* Wg = (const unsigned short*)(wsc + WS_W12T);
  const unsigned short* A2p = (const unsigned short*)(wsc + WS_A2P);

  if (tid < 128) {
    sBW[tid] = wsc[WS_BW + tid];
    if (tid < N_NODES) rs1[tid] = wsc[WS_RS1 + tid];
  } else {
    sB2[tid - 128] = b2[tid - 128];
  }

  short8 bfr[2][4];
  load_bfr(Wg, wv, quad, l16, bfr);

  // ---- Stage 1: Y = X * W12, A-fragments straight from global.
  // afr(lane; mt,ks) = bf16(x[g][n][v0..v0+8)), arow = mt*16+l16,
  // g = arow/28, n = arow%28 (n>=25 -> zero pad), v0 = ((ks*4+quad))*8.
  const float* xb = x + (bq * 4 * T_DIM + t) * GNV;
  f32x4 acc[7][2];
#pragma unroll
  for (int mt = 0; mt < 7; mt++)
#pragma unroll
    for (int nt = 0; nt < 2; nt++)
#pragma unroll
      for (int r = 0; r < 4; r++) acc[mt][nt][r] = 0.f;

#pragma unroll
  for (int ks = 0; ks < 4; ks++) {
    const int cc = (ks << 2) | quad;
    const int v0 = cc << 3;
#pragma unroll
    for (int mt = 0; mt < 7; mt++) {
      int arow = mt * 16 + l16;
      int g = (arow * 586) >> 14;          // arow/28, exact for arow<112
      int n = arow - g * 28;
      short8 afr;
      if (n < N_NODES) {
        const float* xp = xb + g * (T_DIM * GNV) + n * 128 + v0;
        float4 f0 = *(const float4*)xp;
        float4 f1 = *(const float4*)(xp + 4);
        uint4 w;
        w.x = pack2bf(f0.x, f0.y); w.y = pack2bf(f0.z, f0.w);
        w.z = pack2bf(f1.x, f1.y); w.w = pack2bf(f1.z, f1.w);
        afr = __builtin_bit_cast(short8, w);
      } else {
        uint4 w; w.x = 0u; w.y = 0u; w.z = 0u; w.w = 0u;
        afr = __builtin_bit_cast(short8, w);
      }
#pragma unroll
      for (int nt = 0; nt < 2; nt++)
        acc[mt][nt] = __builtin_amdgcn_mfma_f32_16x16x32_bf16(afr, bfr[nt][ks], acc[mt][nt], 0, 0, 0);
    }
  }

  write_yt(LB, acc, wv, quad, l16, tid);
  __syncthreads();                       // Y_T visible to all waves

  short8 a2f[2];
  load_a2f(A2p, quad, l16, a2f);
  const int obase = ((bq * 4 + wv) * T_DIM + t) * GNV;
  float sum = 0.f, ssq = 0.f;
  do_stage2_epi(LB, a2f, sBW, sB2, rs1, hb, obase, wv, quad, l16, sum, ssq);

#pragma unroll
  for (int off = 32; off > 0; off >>= 1) {
    sum += __shfl_down(sum, off, 64);
    ssq += __shfl_down(ssq, off, 64);
  }
  if (lane == 0) { red[wv] = sum; red[4 + wv] = ssq; }
  __syncthreads();
  if (tid == 0) {
    atomicAdd(&stats[t], red[0] + red[1] + red[2] + red[3]);
    atomicAdd(&stats[128 + t], red[4] + red[5] + red[6] + red[7]);
  }
}

// ---------------------------------------------------------------------------
// k_norm_h: read bf16 H (L3-hot), write fp32 out ONCE (non-temporal: out is
// not re-read -> keep x/hb L3-resident).
__global__ __launch_bounds__(256) void k_norm_h(const unsigned short* __restrict__ hb,
                                                const float* __restrict__ stats,
                                                const float* __restrict__ gamma,
                                                const float* __restrict__ beta,
                                                float* __restrict__ out) {
  const int i16 = (blockIdx.x * 256 + threadIdx.x) * 16;
  const int t = (i16 / GNV) % T_DIM;         // 16 consecutive share t (GNV%16==0)
  const float inv = 1.f / CNT_PER_T;
  float s = stats[t], q = stats[128 + t];
  float mean = s * inv;
  float var = fmaf(q, inv, -mean * mean);
  float rstd = rsqrtf(var + 1e-5f);
  float gm = gamma[t] * rstd;
  float bt = fmaf(-mean, gm, beta[t]);
  uint4 h0 = *(const uint4*)(hb + i16);
  uint4 h1 = *(const uint4*)(hb + i16 + 8);
  unsigned int hw[8] = {h0.x, h0.y, h0.z, h0.w, h1.x, h1.y, h1.z, h1.w};
#pragma unroll
  for (int k = 0; k < 4; k++) {
    unsigned int a = hw[2 * k], b = hw[2 * k + 1];
    f32x4 o;
    o[0] = fmaxf(fmaf(bf2f((unsigned short)(a & 0xFFFF)), gm, bt), 0.f);
    o[1] = fmaxf(fmaf(bf2f((unsigned short)(a >> 16)),    gm, bt), 0.f);
    o[2] = fmaxf(fmaf(bf2f((unsigned short)(b & 0xFFFF)), gm, bt), 0.f);
    o[3] = fmaxf(fmaf(bf2f((unsigned short)(b >> 16)),    gm, bt), 0.f);
    __builtin_nontemporal_store(o, (f32x4*)(out + i16 + 4 * k));
  }
}

// ---------------------------------------------------------------------------
// Fallback path (proven round-1/round-5 fp32 variants), used only if ws small.
__device__ __forceinline__ void stage_x_global(unsigned short* __restrict__ LB,
                                               const float* __restrict__ xb, int tid) {
  for (int j = tid; j < 12 * 128; j += 256) {
    int pr = j >> 7;
    int g = pr / 3, rr = pr - (pr / 3) * 3;
    LB[(g * 28 + 25 + rr) * 128 + (j & 127)] = 0;
  }
  for (int idx = tid; idx < 1600; idx += 256) {
    int row = idx >> 4;
    int c8  = (idx & 15) << 3;
    int g = (row * 41) >> 10;
    int n = row - g * 25;
    const float4* xp = (const float4*)(xb + g * (T_DIM * GNV) + n * 128 + c8);
    float4 f0 = xp[0], f1 = xp[1];
    uint4 w;
    w.x = pack2bf(f0.x, f0.y); w.y = pack2bf(f0.z, f0.w);
    w.z = pack2bf(f1.x, f1.y); w.w = pack2bf(f1.z, f1.w);
    int r = g * 28 + n;
    *(uint4*)&LB[r * 128 + (c8 ^ ((r & 15) << 3))] = w;
  }
}

__global__ __launch_bounds__(256, 4) void k_main_f(const float* __restrict__ x,
                                                   const float* __restrict__ b2,
                                                   const float* __restrict__ wsc,
                                                   float* __restrict__ stats,
                                                   float* __restrict__ outf) {
  __shared__ __align__(16) unsigned short LB[4 * YGSTR];
  __shared__ float sBW[128];
  __shared__ float sB2[128];
  __shared__ float rs1[32];
  __shared__ float red[8];
  const int tid = threadIdx.x;
  const int bid = blockIdx.x;
  const int t = bid % T_DIM;
  const int bq = bid / T_DIM;
  const int wv = tid >> 6, lane = tid & 63, quad = lane >> 4, l16 = lane & 15;
  const unsigned short* Wg = (const unsigned short*)(wsc + WS_W12T);
  const unsigned short* A2p = (const unsigned short*)(wsc + WS_A2P);

  if (tid < 128) {
    sBW[tid] = wsc[WS_BW + tid];
    if (tid < N_NODES) rs1[tid] = wsc[WS_RS1 + tid];
  } else {
    sB2[tid - 128] = b2[tid - 128];
  }
  stage_x_global(LB, x + (bq * 4 * T_DIM + t) * GNV, tid);
  short8 bfr[2][4];
  load_bfr(Wg, wv, quad, l16, bfr);
  __syncthreads();
  f32x4 acc[7][2];
#pragma unroll
  for (int mt = 0; mt < 7; mt++)
#pragma unroll
    for (int nt = 0; nt < 2; nt++)
#pragma unroll
      for (int r = 0; r < 4; r++) acc[mt][nt][r] = 0.f;
#pragma unroll
  for (int ks = 0; ks < 4; ks++) {
    const int cc = (ks << 2) | quad;
#pragma unroll
    for (int mt = 0; mt < 7; mt++) {
      int arow = mt * 16 + l16;
      short8 afr = *(const short8*)&LB[arow * 128 + ((cc ^ (arow & 15)) << 3)];
#pragma unroll
      for (int nt = 0; nt < 2; nt++)
        acc[mt][nt] = __builtin_amdgcn_mfma_f32_16x16x32_bf16(afr, bfr[nt][ks], acc[mt][nt], 0, 0, 0);
    }
  }
  __syncthreads();
  write_yt(LB, acc, wv, quad, l16, tid);
  __syncthreads();
  short8 a2f[2];
  load_a2f(A2p, quad, l16, a2f);
  const int obase = ((bq * 4 + wv) * T_DIM + t) * GNV;
  float sum = 0.f, ssq = 0.f;
#pragma unroll
  for (int half = 0; half < 2; half++) {
    f32x4 acc2[2][4];
#pragma unroll
    for (int mt2 = 0; mt2 < 2; mt2++)
#pragma unroll
      for (int nt = 0; nt < 4; nt++)
#pragma unroll
        for (int r = 0; r < 4; r++) acc2[mt2][nt][r] = 0.f;
#pragma unroll
    for (int nt = 0; nt < 4; nt++) {
      int c = (half * 4 + nt) * 16 + l16;
      int base = wv * YGSTR + c * YSTR + quad * 8;
      uint2 lo = *(const uint2*)&LB[base];
      uint2 hi = *(const uint2*)&LB[base + 4];
      uint4 w; w.x = lo.x; w.y = lo.y; w.z = hi.x; w.w = hi.y;
      short8 bf = __builtin_bit_cast(short8, w);
#pragma unroll
      for (int mt2 = 0; mt2 < 2; mt2++)
        acc2[mt2][nt] = __builtin_amdgcn_mfma_f32_16x16x32_bf16(a2f[mt2], bf, acc2[mt2][nt], 0, 0, 0);
    }
#pragma unroll
    for (int mt2 = 0; mt2 < 2; mt2++) {
#pragma unroll
      for (int nt = 0; nt < 4; nt++) {
        int c = (half * 4 + nt) * 16 + l16;
        float bw = sBW[c], bb = sB2[c];
#pragma unroll
        for (int r = 0; r < 4; r++) {
          int m = mt2 * 16 + quad * 4 + r;
          if (m < N_NODES) {
            float v = acc2[mt2][nt][r] + rs1[m] * bw + bb;
            outf[obase + m * 128 + c] = v;
            sum += v;
            ssq += v * v;
          }
        }
      }
    }
  }
#pragma unroll
  for (int off = 32; off > 0; off >>= 1) {
    sum += __shfl_down(sum, off, 64);
    ssq += __shfl_down(ssq, off, 64);
  }
  if (lane == 0) { red[wv] = sum; red[4 + wv] = ssq; }
  __syncthreads();
  if (tid == 0) {
    atomicAdd(&stats[t], red[0] + red[1] + red[2] + red[3]);
    atomicAdd(&stats[128 + t], red[4] + red[5] + red[6] + red[7]);
  }
}

#define NORM_STR  1280000   // float4 stride between a thread's 4 accesses
__global__ __launch_bounds__(256) void k_norm_f(float* __restrict__ out,
                                                const float* __restrict__ stats,
                                                const float* __restrict__ gamma,
                                                const float* __restrict__ beta) {
  const int i0 = blockIdx.x * 256 + threadIdx.x;
  const float inv = 1.f / CNT_PER_T;
  float4 h[4];
  float g[4], bb[4];
  int base[4];
#pragma unroll
  for (int k = 0; k < 4; k++) {
    int i4 = i0 + k * NORM_STR;
    base[k] = i4 * 4;
    int t = (base[k] / GNV) % T_DIM;
    float s = stats[t], q = stats[128 + t];
    float mean = s * inv;
    float var = fmaf(q, inv, -mean * mean);
    float rstd = rsqrtf(var + 1e-5f);
    g[k] = gamma[t] * rstd;
    bb[k] = fmaf(-mean, g[k], beta[t]);
    h[k] = *(const float4*)(out + base[k]);
  }
#pragma unroll
  for (int k = 0; k < 4; k++) {
    float4 v = h[k];
    v.x = fmaxf(fmaf(v.x, g[k], bb[k]), 0.f);
    v.y = fmaxf(fmaf(v.y, g[k], bb[k]), 0.f);
    v.z = fmaxf(fmaf(v.z, g[k], bb[k]), 0.f);
    v.w = fmaxf(fmaf(v.w, g[k], bb[k]), 0.f);
    *(float4*)(out + base[k]) = v;
  }
}

// ---------------------------------------------------------------------------
extern "C" void kernel_launch(void* const* d_in, const int* in_sizes, int n_in,
                              void* d_out, int out_size, void* d_ws, size_t ws_size,
                              hipStream_t stream) {
  const float* x     = (const float*)d_in[0];
  const int*   edge  = (const int*)d_in[1];
  const float* W1    = (const float*)d_in[2];
  const float* b1    = (const float*)d_in[3];
  const float* W2    = (const float*)d_in[4];
  const float* b2    = (const float*)d_in[5];
  const float* gamma = (const float*)d_in[6];
  const float* beta  = (const float*)d_in[7];
  float* out = (float*)d_out;
  float* wsf = (float*)d_ws;

  k_pre<<<65, 256, 0, stream>>>(edge, W1, W2, b1, wsf);

  const size_t need = (size_t)WS_HB * 4 + (size_t)TOT_ELEM * 2;
  if (ws_size >= need) {
    unsigned short* hb = (unsigned short*)(wsf + WS_HB);
    k_main_h3<<<G_TOTAL / 4, 256, 0, stream>>>(x, b2, wsf, wsf + WS_SUM, hb);
    k_norm_h<<<TOT_ELEM / (256 * 16), 256, 0, stream>>>(hb, wsf + WS_SUM, gamma, beta, out);
  } else {
    k_main_f<<<G_TOTAL / 4, 256, 0, stream>>>(x, b2, wsf, wsf + WS_SUM, out);
    k_norm_f<<<NORM_STR / 256, 256, 0, stream>>>(out, wsf + WS_SUM, gamma, beta);
  }
}

// Round 10
// 199.800 us; speedup vs baseline: 1.2934x; 1.2905x over previous
//
#include <hip/hip_runtime.h>

// Problem constants
#define T_DIM   100
#define N_NODES 25
#define C_DIM   128
#define G_TOTAL 6400          // B*T
#define GNV     3200          // N_NODES * C_DIM (per-graph elements)
#define TOT_ELEM 20480000     // G_TOTAL * GNV
#define CNT_PER_T 204800.0f   // B * N * C

// ws float offsets
#define WS_A2P  0             // 1024 bf16 (512 floats): A2 bf16, zero-padded 32x32 [m][k]
#define WS_RS1  640           // 25 floats: rowsum(Ahat)
#define WS_BW   768           // 128 floats: W2^T b1
#define WS_SUM  1024          // 100 floats: per-t sum   (zeroed each call)
#define WS_SSQ  1152          // 100 floats: per-t sumsq
#define WS_W12T 2048          // 16384 bf16 (= 8192 floats): W12^T, [c][v]
#define WS_HB   16384         // bf16 H buffer (TOT_ELEM ushorts = 40.96 MB), if ws fits

// Y_T layout in LDS: [g][c][row], row-stride 36 shorts (72 B: 18-dword stride,
// gcd(18,32)=2 -> 16-bank spread, 2-way free; 8B-aligned for b64 access).
#define YSTR  36
#define YGSTR (128 * YSTR)    // 4608 shorts per graph

typedef __attribute__((ext_vector_type(8))) short short8;
typedef __attribute__((ext_vector_type(4))) float f32x4;

__device__ __forceinline__ unsigned short f2bf(float f) {
  unsigned int u = __float_as_uint(f);
  u += 0x7FFFu + ((u >> 16) & 1u);   // RNE
  return (unsigned short)(u >> 16);
}
__device__ __forceinline__ float bf2f(unsigned short h) {
  return __uint_as_float(((unsigned int)h) << 16);
}
__device__ __forceinline__ unsigned int pack2bf(float a, float b) {
  return (unsigned int)f2bf(a) | ((unsigned int)f2bf(b) << 16);
}

// ---------------------------------------------------------------------------
// k_pre: blocks 0..63 = W12T/bw prep; block 64 = adjacency prep (independent).
__global__ void k_pre(const int* __restrict__ edge, const float* __restrict__ W1,
                      const float* __restrict__ W2, const float* __restrict__ b1,
                      float* __restrict__ wsf) {
  __shared__ float sA[N_NODES * N_NODES];
  __shared__ float sA2[N_NODES * N_NODES];
  __shared__ float sdeg[N_NODES];
  __shared__ float sdis[N_NODES];
  const int tid = threadIdx.x;  // 256

  if (blockIdx.x < 64) {
    // W12T[c][v] = sum_u W1[v][u]*W2[u][c]  (bf16), bw = W2^T b1.
    int j = blockIdx.x * 256 + tid;          // 16384
    int c = j & 127, v = j >> 7;             // v wave-uniform
    float acc = 0.f;
#pragma unroll 8
    for (int u = 0; u < 128; u++) acc = fmaf(W1[v * 128 + u], W2[u * 128 + c], acc);
    ((unsigned short*)(wsf + WS_W12T))[c * 128 + v] = f2bf(acc);
    if (j < 128) {
      float a2 = 0.f;
      for (int u = 0; u < 128; u++) a2 = fmaf(W2[u * 128 + j], b1[u], a2);
      wsf[WS_BW + j] = a2;
    }
    return;
  }

  // ---- block 64: normalized adjacency, A2 = Ahat^2 (bf16 padded), rowsums.
  if (tid < N_NODES) sdeg[tid] = 0.f;
  for (int j = tid; j < N_NODES * N_NODES; j += 256) sA[j] = 0.f;
  __syncthreads();
  if (tid < 64) atomicAdd(&sdeg[edge[64 + tid]], 1.f);  // tgt occurrences
  __syncthreads();
  if (tid < N_NODES) sdis[tid] = rsqrtf(sdeg[tid] + 1.f);  // +1 self-loop
  __syncthreads();
  if (tid < 64) {
    int s = edge[tid], tg = edge[64 + tid];
    atomicAdd(&sA[tg * N_NODES + s], sdis[s] * sdis[tg]);
  }
  __syncthreads();
  if (tid < N_NODES) atomicAdd(&sA[tid * N_NODES + tid], sdis[tid] * sdis[tid]);
  __syncthreads();
  for (int j = tid; j < N_NODES * N_NODES; j += 256) {
    int n = j / N_NODES, m = j - n * N_NODES;
    float acc = 0.f;
    for (int k = 0; k < N_NODES; k++) acc = fmaf(sA[n * N_NODES + k], sA[k * N_NODES + m], acc);
    sA2[j] = acc;
  }
  __syncthreads();
  // A2 bf16, zero-padded to 32x32 row-major [m][k]
  for (int j = tid; j < 1024; j += 256) {
    int m = j >> 5, k = j & 31;
    float v = (m < N_NODES && k < N_NODES) ? sA2[m * N_NODES + k] : 0.f;
    ((unsigned short*)(wsf + WS_A2P))[j] = f2bf(v);
  }
  if (tid < N_NODES) {
    float rs = 0.f;
    for (int m = 0; m < N_NODES; m++) rs += sA[tid * N_NODES + m];
    wsf[WS_RS1 + tid] = rs;
  }
  if (tid < T_DIM) { wsf[WS_SUM + tid] = 0.f; wsf[WS_SSQ + tid] = 0.f; }
}

// ---------------------------------------------------------------------------
// shared building blocks
__device__ __forceinline__ void load_a2f(const unsigned short* __restrict__ A2p,
                                         int quad, int l16, short8 a2f[2]) {
#pragma unroll
  for (int mt2 = 0; mt2 < 2; mt2++)
    a2f[mt2] = *(const short8*)&A2p[(mt2 * 16 + l16) * 32 + quad * 8];
}

// Stage X (generic block size): zero pad rows + 1600 swizzled 16B chunk writes.
template <int NT>
__device__ __forceinline__ void stage_x_global(unsigned short* __restrict__ LB,
                                               const float* __restrict__ xb, int tid) {
  for (int j = tid; j < 12 * 128; j += NT) {
    int pr = j >> 7;                       // 0..11
    int g = pr / 3, rr = pr - (pr / 3) * 3;
    LB[(g * 28 + 25 + rr) * 128 + (j & 127)] = 0;
  }
  for (int idx = tid; idx < 1600; idx += NT) {
    int row = idx >> 4;                    // 0..99  (4 graphs x 25 rows)
    int c8  = (idx & 15) << 3;             // v0 = 0..120 step 8
    int g = (row * 41) >> 10;              // row / 25 (exact for row<100)
    int n = row - g * 25;
    const float4* xp = (const float4*)(xb + g * (T_DIM * GNV) + n * 128 + c8);
    float4 f0 = xp[0], f1 = xp[1];
    uint4 w;
    w.x = pack2bf(f0.x, f0.y); w.y = pack2bf(f0.z, f0.w);
    w.z = pack2bf(f1.x, f1.y); w.w = pack2bf(f1.z, f1.w);
    int r = g * 28 + n;
    *(uint4*)&LB[r * 128 + (c8 ^ ((r & 15) << 3))] = w;
  }
}

// Stage 2 half: H_g(cols ch*64..+64) = A2 * Y_g + epilogue (bias, bf16, stats).
__device__ __forceinline__ void do_stage2_half(const unsigned short* __restrict__ LB,
    const short8 a2f[2], const float* __restrict__ sBW, const float* __restrict__ sB2,
    const float* __restrict__ rs1, unsigned short* __restrict__ hb, int obase,
    int g, int half, int quad, int l16, float& sum, float& ssq) {
  f32x4 acc2[2][4];
#pragma unroll
  for (int mt2 = 0; mt2 < 2; mt2++)
#pragma unroll
    for (int nt = 0; nt < 4; nt++)
#pragma unroll
      for (int r = 0; r < 4; r++) acc2[mt2][nt][r] = 0.f;

#pragma unroll
  for (int nt = 0; nt < 4; nt++) {
    int c = (half * 4 + nt) * 16 + l16;
    int base = g * YGSTR + c * YSTR + quad * 8;
    uint2 lo = *(const uint2*)&LB[base];
    uint2 hi = *(const uint2*)&LB[base + 4];
    uint4 w; w.x = lo.x; w.y = lo.y; w.z = hi.x; w.w = hi.y;
    short8 bf = __builtin_bit_cast(short8, w);
#pragma unroll
    for (int mt2 = 0; mt2 < 2; mt2++)
      acc2[mt2][nt] = __builtin_amdgcn_mfma_f32_16x16x32_bf16(a2f[mt2], bf, acc2[mt2][nt], 0, 0, 0);
  }
#pragma unroll
  for (int mt2 = 0; mt2 < 2; mt2++) {
#pragma unroll
    for (int nt = 0; nt < 4; nt++) {
      int c = (half * 4 + nt) * 16 + l16;
      float bw = sBW[c], bb = sB2[c];
#pragma unroll
      for (int r = 0; r < 4; r++) {
        int m = mt2 * 16 + quad * 4 + r;
        if (m < N_NODES) {
          float v = acc2[mt2][nt][r] + rs1[m] * bw + bb;
          unsigned short hv = f2bf(v);
          float vq = bf2f(hv);             // stats on rounded H (self-consistent)
          hb[obase + m * 128 + c] = hv;
          sum += vq;
          ssq += vq * vq;
        }
      }
    }
  }
}

// ---------------------------------------------------------------------------
// k_main_w8: 512-thread blocks (8 waves), 4 graphs/block, same LDS (38.4KB).
// Goal: total regs <= 64 -> 4 blocks x 8 waves = 32 waves/CU (2x latency hiding).
// Stage 1: wave wv owns c-tile [wv*16,+16): bfr = 4 short8 (16 regs), acc = 7
// f32x4 (28). Stage 2: wave wv -> graph wv>>1, c-half wv&1.
__global__ __launch_bounds__(512, 8) void k_main_w8(const float* __restrict__ x,
                                                    const float* __restrict__ b2,
                                                    const float* __restrict__ wsc,
                                                    float* __restrict__ stats,
                                                    unsigned short* __restrict__ hb) {
  __shared__ __align__(16) unsigned short LB[4 * YGSTR];  // 36864 B union
  __shared__ float sBW[128];
  __shared__ float sB2[128];
  __shared__ float rs1[32];
  __shared__ float red[16];
  const int tid = threadIdx.x;
  const int bid = blockIdx.x;
  const int t = bid % T_DIM;
  const int bq = bid / T_DIM;
  const int wv = tid >> 6, lane = tid & 63, quad = lane >> 4, l16 = lane & 15;
  const unsigned short* Wg = (const unsigned short*)(wsc + WS_W12T);
  const unsigned short* A2p = (const unsigned short*)(wsc + WS_A2P);

  if (tid < 128) {
    sBW[tid] = wsc[WS_BW + tid];
    if (tid < N_NODES) rs1[tid] = wsc[WS_RS1 + tid];
  } else if (tid < 256) {
    sB2[tid - 128] = b2[tid - 128];
  }

  // stage X to LDS (swizzled bf16)
  stage_x_global<512>(LB, x + (bq * 4 * T_DIM + t) * GNV, tid);

  // B-fragments: wave wv covers c in [wv*16, +16). 4 short8 = 16 VGPR.
  short8 bfr[4];
  {
    const short8* rp = (const short8*)&Wg[(wv * 16 + l16) * 128];
#pragma unroll
    for (int ks = 0; ks < 4; ks++) bfr[ks] = rp[(ks << 2) | quad];
  }
  __syncthreads();

  // ---- Stage 1: Y = X * W12. 28 MFMA/wave (7 mt x 4 ks).
  f32x4 acc[7];
#pragma unroll
  for (int mt = 0; mt < 7; mt++)
#pragma unroll
    for (int r = 0; r < 4; r++) acc[mt][r] = 0.f;

#pragma unroll
  for (int ks = 0; ks < 4; ks++) {
    const int cc = (ks << 2) | quad;
#pragma unroll
    for (int mt = 0; mt < 7; mt++) {
      int arow = mt * 16 + l16;
      short8 afr = *(const short8*)&LB[arow * 128 + ((cc ^ (arow & 15)) << 3)];
      acc[mt] = __builtin_amdgcn_mfma_f32_16x16x32_bf16(afr, bfr[ks], acc[mt], 0, 0, 0);
    }
  }
  __syncthreads();  // all X reads done; LB becomes Y_T

  // Write Y -> Y_T (bf16). Wave wv: col c = wv*16 + l16, rows per mt/quad.
#pragma unroll
  for (int mt = 0; mt < 7; mt++) {
    int row0 = mt * 16 + quad * 4;
    int g = row0 / 28;
    int rl = row0 - g * 28;                // multiple of 4 -> 8B aligned
    int c = wv * 16 + l16;
    uint2 p;
    p.x = pack2bf(acc[mt][0], acc[mt][1]);
    p.y = pack2bf(acc[mt][2], acc[mt][3]);
    *(uint2*)&LB[g * YGSTR + c * YSTR + rl] = p;
  }
  // zero Y_T pad rows 28..31 (512 entries, one per thread)
  {
    uint2 z; z.x = 0u; z.y = 0u;
    int g = tid >> 7, c = tid & 127;
    *(uint2*)&LB[g * YGSTR + c * YSTR + 28] = z;
  }
  __syncthreads();

  // ---- Stage 2: wave wv -> graph wv>>1, c-half wv&1. 8 MFMA/wave.
  short8 a2f[2];
  load_a2f(A2p, quad, l16, a2f);
  const int g2 = wv >> 1, ch = wv & 1;
  const int obase = ((bq * 4 + g2) * T_DIM + t) * GNV;
  float sum = 0.f, ssq = 0.f;
  do_stage2_half(LB, a2f, sBW, sB2, rs1, hb, obase, g2, ch, quad, l16, sum, ssq);

#pragma unroll
  for (int off = 32; off > 0; off >>= 1) {
    sum += __shfl_down(sum, off, 64);
    ssq += __shfl_down(ssq, off, 64);
  }
  if (lane == 0) { red[wv] = sum; red[8 + wv] = ssq; }
  __syncthreads();
  if (tid == 0) {
    float bs = 0.f, bq2 = 0.f;
#pragma unroll
    for (int w = 0; w < 8; w++) { bs += red[w]; bq2 += red[8 + w]; }
    atomicAdd(&stats[t], bs);
    atomicAdd(&stats[128 + t], bq2);
  }
}

// ---------------------------------------------------------------------------
// k_norm_h: read bf16 H (L3-hot), write fp32 out ONCE. 8 elems/thread.
// (R5-proven form: plain stores.)
__global__ __launch_bounds__(256) void k_norm_h(const unsigned short* __restrict__ hb,
                                                const float* __restrict__ stats,
                                                const float* __restrict__ gamma,
                                                const float* __restrict__ beta,
                                                float* __restrict__ out) {
  const int i8 = (blockIdx.x * 256 + threadIdx.x) * 8;
  const int t = (i8 / GNV) % T_DIM;          // 8 consecutive share t (GNV%8==0)
  const float inv = 1.f / CNT_PER_T;
  float s = stats[t], q = stats[128 + t];
  float mean = s * inv;
  float var = fmaf(q, inv, -mean * mean);
  float rstd = rsqrtf(var + 1e-5f);
  float gm = gamma[t] * rstd;
  float bt = fmaf(-mean, gm, beta[t]);
  uint4 hw = *(const uint4*)(hb + i8);       // 8 bf16
  float4 o0, o1;
  o0.x = fmaxf(fmaf(bf2f((unsigned short)(hw.x & 0xFFFF)), gm, bt), 0.f);
  o0.y = fmaxf(fmaf(bf2f((unsigned short)(hw.x >> 16)),    gm, bt), 0.f);
  o0.z = fmaxf(fmaf(bf2f((unsigned short)(hw.y & 0xFFFF)), gm, bt), 0.f);
  o0.w = fmaxf(fmaf(bf2f((unsigned short)(hw.y >> 16)),    gm, bt), 0.f);
  o1.x = fmaxf(fmaf(bf2f((unsigned short)(hw.z & 0xFFFF)), gm, bt), 0.f);
  o1.y = fmaxf(fmaf(bf2f((unsigned short)(hw.z >> 16)),    gm, bt), 0.f);
  o1.z = fmaxf(fmaf(bf2f((unsigned short)(hw.w & 0xFFFF)), gm, bt), 0.f);
  o1.w = fmaxf(fmaf(bf2f((unsigned short)(hw.w >> 16)),    gm, bt), 0.f);
  *(float4*)(out + i8) = o0;
  *(float4*)(out + i8 + 4) = o1;
}

// ---------------------------------------------------------------------------
// Fallback path (proven fp32 variants), used only if ws is too small.
__global__ __launch_bounds__(256, 4) void k_main_f(const float* __restrict__ x,
                                                   const float* __restrict__ b2,
                                                   const float* __restrict__ wsc,
                                                   float* __restrict__ stats,
                                                   float* __restrict__ outf) {
  __shared__ __align__(16) unsigned short LB[4 * YGSTR];
  __shared__ float sBW[128];
  __shared__ float sB2[128];
  __shared__ float rs1[32];
  __shared__ float red[8];
  const int tid = threadIdx.x;
  const int bid = blockIdx.x;
  const int t = bid % T_DIM;
  const int bq = bid / T_DIM;
  const int wv = tid >> 6, lane = tid & 63, quad = lane >> 4, l16 = lane & 15;
  const unsigned short* Wg = (const unsigned short*)(wsc + WS_W12T);
  const unsigned short* A2p = (const unsigned short*)(wsc + WS_A2P);

  if (tid < 128) {
    sBW[tid] = wsc[WS_BW + tid];
    if (tid < N_NODES) rs1[tid] = wsc[WS_RS1 + tid];
  } else {
    sB2[tid - 128] = b2[tid - 128];
  }
  stage_x_global<256>(LB, x + (bq * 4 * T_DIM + t) * GNV, tid);
  short8 bfr[2][4];
  {
#pragma unroll
    for (int nt = 0; nt < 2; nt++) {
      const short8* rp = (const short8*)&Wg[(wv * 32 + nt * 16 + l16) * 128];
#pragma unroll
      for (int ks = 0; ks < 4; ks++) bfr[nt][ks] = rp[(ks << 2) | quad];
    }
  }
  __syncthreads();
  f32x4 acc[7][2];
#pragma unroll
  for (int mt = 0; mt < 7; mt++)
#pragma unroll
    for (int nt = 0; nt < 2; nt++)
#pragma unroll
      for (int r = 0; r < 4; r++) acc[mt][nt][r] = 0.f;
#pragma unroll
  for (int ks = 0; ks < 4; ks++) {
    const int cc = (ks << 2) | quad;
#pragma unroll
    for (int mt = 0; mt < 7; mt++) {
      int arow = mt * 16 + l16;
      short8 afr = *(const short8*)&LB[arow * 128 + ((cc ^ (arow & 15)) << 3)];
#pragma unroll
      for (int nt = 0; nt < 2; nt++)
        acc[mt][nt] = __builtin_amdgcn_mfma_f32_16x16x32_bf16(afr, bfr[nt][ks], acc[mt][nt], 0, 0, 0);
    }
  }
  __syncthreads();
#pragma unroll
  for (int mt = 0; mt < 7; mt++) {
    int row0 = mt * 16 + quad * 4;
    int g = row0 / 28;
    int rl = row0 - g * 28;
#pragma unroll
    for (int nt = 0; nt < 2; nt++) {
      int c = wv * 32 + nt * 16 + l16;
      uint2 p;
      p.x = pack2bf(acc[mt][nt][0], acc[mt][nt][1]);
      p.y = pack2bf(acc[mt][nt][2], acc[mt][nt][3]);
      *(uint2*)&LB[g * YGSTR + c * YSTR + rl] = p;
    }
  }
  {
    uint2 z; z.x = 0u; z.y = 0u;
    for (int j = tid; j < 512; j += 256) {
      int g = j >> 7, c = j & 127;
      *(uint2*)&LB[g * YGSTR + c * YSTR + 28] = z;
    }
  }
  __syncthreads();
  short8 a2f[2];
  load_a2f(A2p, quad, l16, a2f);
  const int obase = ((bq * 4 + wv) * T_DIM + t) * GNV;
  float sum = 0.f, ssq = 0.f;
#pragma unroll
  for (int half = 0; half < 2; half++) {
    f32x4 acc2[2][4];
#pragma unroll
    for (int mt2 = 0; mt2 < 2; mt2++)
#pragma unroll
      for (int nt = 0; nt < 4; nt++)
#pragma unroll
        for (int r = 0; r < 4; r++) acc2[mt2][nt][r] = 0.f;
#pragma unroll
    for (int nt = 0; nt < 4; nt++) {
      int c = (half * 4 + nt) * 16 + l16;
      int base = wv * YGSTR + c * YSTR + quad * 8;
      uint2 lo = *(const uint2*)&LB[base];
      uint2 hi = *(const uint2*)&LB[base + 4];
      uint4 w; w.x = lo.x; w.y = lo.y; w.z = hi.x; w.w = hi.y;
      short8 bf = __builtin_bit_cast(short8, w);
#pragma unroll
      for (int mt2 = 0; mt2 < 2; mt2++)
        acc2[mt2][nt] = __builtin_amdgcn_mfma_f32_16x16x32_bf16(a2f[mt2], bf, acc2[mt2][nt], 0, 0, 0);
    }
#pragma unroll
    for (int mt2 = 0; mt2 < 2; mt2++) {
#pragma unroll
      for (int nt = 0; nt < 4; nt++) {
        int c = (half * 4 + nt) * 16 + l16;
        float bw = sBW[c], bb = sB2[c];
#pragma unroll
        for (int r = 0; r < 4; r++) {
          int m = mt2 * 16 + quad * 4 + r;
          if (m < N_NODES) {
            float v = acc2[mt2][nt][r] + rs1[m] * bw + bb;
            outf[obase + m * 128 + c] = v;
            sum += v;
            ssq += v * v;
          }
        }
      }
    }
  }
#pragma unroll
  for (int off = 32; off > 0; off >>= 1) {
    sum += __shfl_down(sum, off, 64);
    ssq += __shfl_down(ssq, off, 64);
  }
  if (lane == 0) { red[wv] = sum; red[4 + wv] = ssq; }
  __syncthreads();
  if (tid == 0) {
    atomicAdd(&stats[t], red[0] + red[1] + red[2] + red[3]);
    atomicAdd(&stats[128 + t], red[4] + red[5] + red[6] + red[7]);
  }
}

#define NORM_STR  1280000   // float4 stride between a thread's 4 accesses
__global__ __launch_bounds__(256) void k_norm_f(float* __restrict__ out,
                                                const float* __restrict__ stats,
                                                const float* __restrict__ gamma,
                                                const float* __restrict__ beta) {
  const int i0 = blockIdx.x * 256 + threadIdx.x;
  const float inv = 1.f / CNT_PER_T;
  float4 h[4];
  float g[4], bb[4];
  int base[4];
#pragma unroll
  for (int k = 0; k < 4; k++) {
    int i4 = i0 + k * NORM_STR;
    base[k] = i4 * 4;
    int t = (base[k] / GNV) % T_DIM;
    float s = stats[t], q = stats[128 + t];
    float mean = s * inv;
    float var = fmaf(q, inv, -mean * mean);
    float rstd = rsqrtf(var + 1e-5f);
    g[k] = gamma[t] * rstd;
    bb[k] = fmaf(-mean, g[k], beta[t]);
    h[k] = *(const float4*)(out + base[k]);
  }
#pragma unroll
  for (int k = 0; k < 4; k++) {
    float4 v = h[k];
    v.x = fmaxf(fmaf(v.x, g[k], bb[k]), 0.f);
    v.y = fmaxf(fmaf(v.y, g[k], bb[k]), 0.f);
    v.z = fmaxf(fmaf(v.z, g[k], bb[k]), 0.f);
    v.w = fmaxf(fmaf(v.w, g[k], bb[k]), 0.f);
    *(float4*)(out + base[k]) = v;
  }
}

// ---------------------------------------------------------------------------
extern "C" void kernel_launch(void* const* d_in, const int* in_sizes, int n_in,
                              void* d_out, int out_size, void* d_ws, size_t ws_size,
                              hipStream_t stream) {
  const float* x     = (const float*)d_in[0];
  const int*   edge  = (const int*)d_in[1];
  const float* W1    = (const float*)d_in[2];
  const float* b1    = (const float*)d_in[3];
  const float* W2    = (const float*)d_in[4];
  const float* b2    = (const float*)d_in[5];
  const float* gamma = (const float*)d_in[6];
  const float* beta  = (const float*)d_in[7];
  float* out = (float*)d_out;
  float* wsf = (float*)d_ws;

  k_pre<<<65, 256, 0, stream>>>(edge, W1, W2, b1, wsf);

  const size_t need = (size_t)WS_HB * 4 + (size_t)TOT_ELEM * 2;
  if (ws_size >= need) {
    unsigned short* hb = (unsigned short*)(wsf + WS_HB);
    k_main_w8<<<G_TOTAL / 4, 512, 0, stream>>>(x, b2, wsf, wsf + WS_SUM, hb);
    k_norm_h<<<TOT_ELEM / (256 * 8), 256, 0, stream>>>(hb, wsf + WS_SUM, gamma, beta, out);
  } else {
    k_main_f<<<G_TOTAL / 4, 256, 0, stream>>>(x, b2, wsf, wsf + WS_SUM, out);
    k_norm_f<<<NORM_STR / 256, 256, 0, stream>>>(out, wsf + WS_SUM, gamma, beta);
  }
}